// Round 3
// baseline (31.107 us; speedup 1.0000x reference)
//
#include <hip/hip_runtime.h>

typedef _Float16 f16;
typedef __attribute__((ext_vector_type(2))) _Float16 f16x2;
typedef __attribute__((ext_vector_type(4))) _Float16 f16x4;
typedef __attribute__((ext_vector_type(8))) _Float16 f16x8;
typedef __attribute__((ext_vector_type(4))) float f32x4;
typedef __attribute__((ext_vector_type(4))) unsigned u32x4;

constexpr int IN_F  = 4096;
constexpr int OUT_F = 11008;
constexpr int NGRP  = 32;   // 4096 / 128

// x [8][4096] fp32 -> f16 in workspace
__global__ void xprep_kernel(const float* __restrict__ x, f16* __restrict__ xh) {
    int i = (blockIdx.x * blockDim.x + threadIdx.x) * 4;
    float4 v = *(const float4*)(x + i);
    f16x4 r = {(f16)v.x, (f16)v.y, (f16)v.z, (f16)v.w};
    *(f16x4*)(xh + i) = r;
}

// dequant one byte-holding int32 (2 nibbles) -> 2 packed f16 weights
__device__ __forceinline__ unsigned dq2(unsigned q, f16x2 sp, f16x2 zp) {
    unsigned t = (((q << 12) | q) & 0x000F000Fu) | 0x64006400u;  // (1024+lo, 1024+hi)
    f16x2 u = __builtin_bit_cast(f16x2, t);
    u = u - (f16x2){(_Float16)1024.0f, (_Float16)1024.0f};       // exact: (lo, hi)
    u = u * sp + zp;                                             // v_pk_fma_f16
    return __builtin_bit_cast(unsigned, u);
}

__device__ __forceinline__ f16x2 bcast(float v) {
    _Float16 h = (_Float16)v;
    return (f16x2){h, h};
}

// One block = one 16-wide output tile, 256 threads (4 waves), wave splits K 4-way
// (1024 k each = 8 quant groups). Full-grid residency: 688 blocks, 4 blocks/CU cap.
// MFMA 16x16x32 f16: lane&15 -> A row m / B col n; k = 8*(lane>>4)+i contiguous.
template<bool PRE>
__global__ __launch_bounds__(256, 4)
void qlin_kernel(const int* __restrict__ wq,
                 const float* __restrict__ scales,
                 const float* __restrict__ zeros,
                 const float* __restrict__ bias,
                 const float* __restrict__ xf,
                 const f16* __restrict__ xh,
                 float* __restrict__ out)
{
    __shared__ f32x4 red[4][64];
    const int tid  = threadIdx.x;
    const int wv   = tid >> 6;       // 0..3
    const int lane = tid & 63;
    const int col  = lane & 15;
    const int kg   = lane >> 4;
    const int o0   = blockIdx.x * 16;
    const int orow = o0 + col;
    const bool mvalid = (col < 8);

    const int kbase = wv * 1024;
    const int g0    = kbase >> 7;    // wv*8

    // per-wave scales/zeros: 8 contiguous groups
    float4 sa = *(const float4*)(scales + (size_t)orow * NGRP + g0);
    float4 sb = *(const float4*)(scales + (size_t)orow * NGRP + g0 + 4);
    float4 za = *(const float4*)(zeros  + (size_t)orow * NGRP + g0);
    float4 zb = *(const float4*)(zeros  + (size_t)orow * NGRP + g0 + 4);
    f16x2 sp[8] = {bcast(sa.x), bcast(sa.y), bcast(sa.z), bcast(sa.w),
                   bcast(sb.x), bcast(sb.y), bcast(sb.z), bcast(sb.w)};
    f16x2 zp[8] = {bcast(za.x), bcast(za.y), bcast(za.z), bcast(za.w),
                   bcast(zb.x), bcast(zb.y), bcast(zb.z), bcast(zb.w)};

    const int*   wbase = wq + (size_t)orow * (IN_F / 2) + (kbase >> 1) + kg * 4;
    const f16*   xrow  = xh + (size_t)col * IN_F + kbase + kg * 8;
    const float* xfrow = xf + (size_t)col * IN_F + kbase + kg * 8;

    f32x4 acc = {0.f, 0.f, 0.f, 0.f};

    int4  qb[2][4];
    f16x8 ab[2][4];

    // prologue: load group 0 (4 k-tiles of weights + A-frags)
    #pragma unroll
    for (int t = 0; t < 4; ++t) {
        qb[0][t] = *(const int4*)(wbase + t * 16);
        if (mvalid) {
            if constexpr (PRE) {
                ab[0][t] = *(const f16x8*)(xrow + t * 32);
            } else {
                float4 a0 = *(const float4*)(xfrow + t * 32);
                float4 a1 = *(const float4*)(xfrow + t * 32 + 4);
                ab[0][t] = (f16x8){(f16)a0.x,(f16)a0.y,(f16)a0.z,(f16)a0.w,
                                   (f16)a1.x,(f16)a1.y,(f16)a1.z,(f16)a1.w};
            }
        } else {
            ab[0][t] = (f16x8){0,0,0,0,0,0,0,0};
        }
    }

    #pragma unroll
    for (int gl = 0; gl < 8; ++gl) {
        const int cur = gl & 1, nxt = cur ^ 1;
        if (gl < 7) {
            #pragma unroll
            for (int t = 0; t < 4; ++t) {
                qb[nxt][t] = *(const int4*)(wbase + (gl + 1) * 64 + t * 16);
                if (mvalid) {
                    if constexpr (PRE) {
                        ab[nxt][t] = *(const f16x8*)(xrow + (gl + 1) * 128 + t * 32);
                    } else {
                        float4 a0 = *(const float4*)(xfrow + (gl + 1) * 128 + t * 32);
                        float4 a1 = *(const float4*)(xfrow + (gl + 1) * 128 + t * 32 + 4);
                        ab[nxt][t] = (f16x8){(f16)a0.x,(f16)a0.y,(f16)a0.z,(f16)a0.w,
                                             (f16)a1.x,(f16)a1.y,(f16)a1.z,(f16)a1.w};
                    }
                } else {
                    ab[nxt][t] = (f16x8){0,0,0,0,0,0,0,0};
                }
            }
        }
        const f16x2 s2 = sp[gl], z2 = zp[gl];
        #pragma unroll
        for (int t = 0; t < 4; ++t) {
            const int4 q = qb[cur][t];
            u32x4 bw = {dq2((unsigned)q.x, s2, z2),
                        dq2((unsigned)q.y, s2, z2),
                        dq2((unsigned)q.z, s2, z2),
                        dq2((unsigned)q.w, s2, z2)};
            f16x8 bfr = __builtin_bit_cast(f16x8, bw);
            acc = __builtin_amdgcn_mfma_f32_16x16x32_f16(ab[cur][t], bfr, acc, 0, 0, 0);
        }
    }

    red[wv][lane] = acc;
    __syncthreads();

    if (tid < 64) {
        f32x4 ssum = red[0][tid];
        #pragma unroll
        for (int w = 1; w < 4; ++w) ssum += red[w][tid];
        const int n = tid & 15;
        const float bb = bias[o0 + n];
        const int mbase = (tid >> 4) * 4;   // C/D row = (lane>>4)*4 + reg
        if (mbase < 8) {
            #pragma unroll
            for (int i = 0; i < 4; ++i)
                out[(size_t)(mbase + i) * OUT_F + o0 + n] = ssum[i] + bb;
        }
    }
}

extern "C" void kernel_launch(void* const* d_in, const int* in_sizes, int n_in,
                              void* d_out, int out_size, void* d_ws, size_t ws_size,
                              hipStream_t stream) {
    const float* x  = (const float*)d_in[0];
    const int*   wq = (const int*)d_in[1];
    const float* sc = (const float*)d_in[2];
    const float* zr = (const float*)d_in[3];
    const float* bs = (const float*)d_in[4];
    float* out = (float*)d_out;

    if (ws_size >= (size_t)(8 * IN_F * sizeof(f16))) {
        f16* xh = (f16*)d_ws;
        xprep_kernel<<<(8 * IN_F) / (256 * 4), 256, 0, stream>>>(x, xh);
        qlin_kernel<true><<<OUT_F / 16, 256, 0, stream>>>(wq, sc, zr, bs, x, xh, out);
    } else {
        qlin_kernel<false><<<OUT_F / 16, 256, 0, stream>>>(wq, sc, zr, bs, x, (const f16*)d_ws, out);
    }
}

// Round 4
// 30.418 us; speedup vs baseline: 1.0227x; 1.0227x over previous
//
#include <hip/hip_runtime.h>

typedef _Float16 f16;
typedef __attribute__((ext_vector_type(2))) _Float16 f16x2;
typedef __attribute__((ext_vector_type(4))) _Float16 f16x4;
typedef __attribute__((ext_vector_type(8))) _Float16 f16x8;
typedef __attribute__((ext_vector_type(4))) float f32x4;
typedef __attribute__((ext_vector_type(4))) unsigned u32x4;

constexpr int IN_F  = 4096;
constexpr int OUT_F = 11008;
constexpr int NGRP  = 32;   // 4096 / 128

// x [8][4096] fp32 -> f16 in workspace
__global__ void xprep_kernel(const float* __restrict__ x, f16* __restrict__ xh) {
    int i = (blockIdx.x * blockDim.x + threadIdx.x) * 4;
    float4 v = *(const float4*)(x + i);
    f16x4 r = {(f16)v.x, (f16)v.y, (f16)v.z, (f16)v.w};
    *(f16x4*)(xh + i) = r;
}

// dequant one byte-holding int32 (2 nibbles) -> 2 packed f16 weights
__device__ __forceinline__ unsigned dq2(unsigned q, f16x2 sp, f16x2 zp) {
    unsigned t = (((q << 12) | q) & 0x000F000Fu) | 0x64006400u;  // (1024+lo, 1024+hi)
    f16x2 u = __builtin_bit_cast(f16x2, t);
    u = u - (f16x2){(_Float16)1024.0f, (_Float16)1024.0f};       // exact
    u = u * sp + zp;                                             // v_pk_fma_f16
    return __builtin_bit_cast(unsigned, u);
}

__device__ __forceinline__ f16x2 bcast(float v) {
    _Float16 h = (_Float16)v;
    return (f16x2){h, h};
}

// Block = 16-row o-tile, 256 threads (4 waves). Weights staged via
// global_load_lds: each wave-instruction reads ONE row's contiguous 1KB
// (lane i -> bytes i*16), source pre-swizzled with ^((row&7)<<4) so the
// swizzled ds_read is bank-balanced (both-sides-or-neither, m173/m201).
// Slab = 512 k (16 rows x 1KB = 16KB), double-buffered. Wave w owns quant
// group 4s+w of slab s (4 MFMA k-tiles of 32).
template<bool PRE>
__global__ __launch_bounds__(256, 4)
void qlin_kernel(const int* __restrict__ wq,
                 const float* __restrict__ scales,
                 const float* __restrict__ zeros,
                 const float* __restrict__ bias,
                 const float* __restrict__ xf,
                 const f16* __restrict__ xh,
                 float* __restrict__ out)
{
    __shared__ unsigned char wlds[2][16][1024];   // 32 KB
    __shared__ f32x4 red[4][64];

    const int tid  = threadIdx.x;
    const int wv   = tid >> 6;       // 0..3
    const int lane = tid & 63;
    const int col  = lane & 15;      // B col n = weight row; A row m
    const int kg   = lane >> 4;      // k sub-chunk
    const int o0   = blockIdx.x * 16;
    const int orow = o0 + col;
    const bool mvalid = (col < 8);

    // this wave's 8 quant groups: g = s*4 + wv
    f16x2 sp[8], zp[8];
    #pragma unroll
    for (int s = 0; s < 8; ++s) {
        sp[s] = bcast(scales[(size_t)orow * NGRP + s * 4 + wv]);
        zp[s] = bcast(zeros [(size_t)orow * NGRP + s * 4 + wv]);
    }

    const char* wtile = (const char*)wq + (size_t)o0 * 8192;   // 8192 B per row

    // stage slab sl into buffer bufi: wave wv stages rows 4wv..4wv+3,
    // one full contiguous 1KB row per instruction, source XOR-swizzled.
    auto stage = [&](int sl, int bufi) {
        #pragma unroll
        for (int c = 0; c < 4; ++c) {
            const int r = 4 * wv + c;
            const char* src = wtile + (size_t)r * 8192 + sl * 1024
                              + ((lane * 16) ^ ((r & 7) << 4));
            __builtin_amdgcn_global_load_lds(
                (const __attribute__((address_space(1))) void*)src,
                (__attribute__((address_space(3))) void*)&wlds[bufi][r][0],
                16, 0, 0);
        }
    };

    stage(0, 0);

    const f16*   xcol  = xh + (size_t)col * IN_F;
    const float* xfcol = xf + (size_t)col * IN_F;
    const unsigned swz = (unsigned)((col & 7) << 4);

    f32x4 acc = {0.f, 0.f, 0.f, 0.f};

    __syncthreads();   // drains stage(0)

    #pragma unroll
    for (int s = 0; s < 8; ++s) {
        const int cur = s & 1;
        if (s < 7) stage(s + 1, cur ^ 1);

        // A fragments for this slab (k = s*512 + wv*128 + t*32 + kg*8)
        f16x8 af[4];
        #pragma unroll
        for (int t = 0; t < 4; ++t) {
            const int k = s * 512 + wv * 128 + t * 32 + kg * 8;
            if (mvalid) {
                if constexpr (PRE) {
                    af[t] = *(const f16x8*)(xcol + k);
                } else {
                    float4 a0 = *(const float4*)(xfcol + k);
                    float4 a1 = *(const float4*)(xfcol + k + 4);
                    af[t] = (f16x8){(f16)a0.x,(f16)a0.y,(f16)a0.z,(f16)a0.w,
                                    (f16)a1.x,(f16)a1.y,(f16)a1.z,(f16)a1.w};
                }
            } else {
                af[t] = (f16x8){0,0,0,0,0,0,0,0};
            }
        }

        const f16x2 s2 = sp[s], z2 = zp[s];
        #pragma unroll
        for (int t = 0; t < 4; ++t) {
            const unsigned off = ((unsigned)(wv * 256 + t * 64 + kg * 16)) ^ swz;
            const int4 q = *(const int4*)&wlds[cur][col][off];
            u32x4 bw = {dq2((unsigned)q.x, s2, z2),
                        dq2((unsigned)q.y, s2, z2),
                        dq2((unsigned)q.z, s2, z2),
                        dq2((unsigned)q.w, s2, z2)};
            f16x8 bfr = __builtin_bit_cast(f16x8, bw);
            acc = __builtin_amdgcn_mfma_f32_16x16x32_f16(af[t], bfr, acc, 0, 0, 0);
        }

        __syncthreads();   // drains stage(s+1) writes + protects buffer reuse
    }

    red[wv][lane] = acc;
    __syncthreads();

    if (tid < 64) {
        f32x4 ssum = red[0][tid];
        #pragma unroll
        for (int w = 1; w < 4; ++w) ssum += red[w][tid];
        const int n = tid & 15;
        const float bb = bias[o0 + n];
        const int mbase = (tid >> 4) * 4;   // C/D row = (lane>>4)*4 + reg
        if (mbase < 8) {
            #pragma unroll
            for (int i = 0; i < 4; ++i)
                out[(size_t)(mbase + i) * OUT_F + o0 + n] = ssum[i] + bb;
        }
    }
}

extern "C" void kernel_launch(void* const* d_in, const int* in_sizes, int n_in,
                              void* d_out, int out_size, void* d_ws, size_t ws_size,
                              hipStream_t stream) {
    const float* x  = (const float*)d_in[0];
    const int*   wq = (const int*)d_in[1];
    const float* sc = (const float*)d_in[2];
    const float* zr = (const float*)d_in[3];
    const float* bs = (const float*)d_in[4];
    float* out = (float*)d_out;

    if (ws_size >= (size_t)(8 * IN_F * sizeof(f16))) {
        f16* xh = (f16*)d_ws;
        xprep_kernel<<<(8 * IN_F) / (256 * 4), 256, 0, stream>>>(x, xh);
        qlin_kernel<true><<<OUT_F / 16, 256, 0, stream>>>(wq, sc, zr, bs, x, xh, out);
    } else {
        qlin_kernel<false><<<OUT_F / 16, 256, 0, stream>>>(wq, sc, zr, bs, x, (const f16*)d_ws, out);
    }
}